// Round 1
// baseline (874.509 us; speedup 1.0000x reference)
//
#include <hip/hip_runtime.h>
#include <float.h>

#define NN 16384
#define DD 128
#define KK 64
#define N_ITERS 10
#define NCH 16
#define CHROWS (NN / NCH)
#define EPSN 1e-12f
#define TOL2 1e-8f   // (1e-4)^2
#define MOM 0.9f
#define MOM1 0.1f

__device__ __forceinline__ bool gt_pair(float v, int i, float w, int j) {
  // strict "better than": higher value, ties broken by lower index (stable argmax/top_k)
  return (v > w) || (v == w && i < j);
}

// ---- init: inverse row norms of embeddings; reset done flag (every call!)
__global__ __launch_bounds__(256) void k_init(const float* __restrict__ E,
                                              float* __restrict__ invn,
                                              int* __restrict__ done) {
  int i = blockIdx.x * 256 + threadIdx.x;
  if (i == 0) *done = 0;
  const float4* rp = (const float4*)(E + (size_t)i * DD);
  float s = 0.f;
#pragma unroll
  for (int q = 0; q < 32; ++q) {
    float4 v = rp[q];
    s += v.x * v.x + v.y * v.y + v.z * v.z + v.w * v.w;
  }
  invn[i] = 1.0f / fmaxf(sqrtf(s), EPSN);
}

// ---- labels / final-sim kernel.
// grid = NN*4/256 blocks of 256. Each thread: one row x 16 centroids.
// MODE 0: write labels (argmax centroid). MODE 1: write sim matrix + negidx (2nd-best centroid).
template <int MODE>
__global__ __launch_bounds__(256, 1) void k_labels(
    const float* __restrict__ E, const float* __restrict__ invn,
    const float* __restrict__ c, int* __restrict__ labels,
    int* __restrict__ negidx, float* __restrict__ sim) {
  __shared__ float cs[KK * DD];
  __shared__ float cinv[KK];
  for (int q = threadIdx.x; q < KK * DD / 4; q += 256)
    ((float4*)cs)[q] = ((const float4*)c)[q];
  __syncthreads();
  if (threadIdx.x < KK) {
    const float4* cm = (const float4*)(cs + threadIdx.x * DD);
    float s = 0.f;
#pragma unroll
    for (int q = 0; q < 32; ++q) {
      float4 v = cm[q];
      s += v.x * v.x + v.y * v.y + v.z * v.z + v.w * v.w;
    }
    cinv[threadIdx.x] = 1.0f / fmaxf(sqrtf(s), EPSN);
  }
  __syncthreads();
  for (int q = threadIdx.x; q < KK * DD; q += 256) cs[q] *= cinv[q >> 7];
  __syncthreads();

  int g = blockIdx.x * 256 + threadIdx.x;
  int row = g >> 2;
  int cg = g & 3;
  float inv = invn[row];
  float4 rv[32];  // whole row in registers (128 VGPRs), statically indexed
  const float4* rp = (const float4*)(E + (size_t)row * DD);
#pragma unroll
  for (int q = 0; q < 32; ++q) {
    float4 v = rp[q];
    v.x *= inv; v.y *= inv; v.z *= inv; v.w *= inv;
    rv[q] = v;
  }
  float b1 = -3.0e38f, b2 = -3.0e38f;
  int i1 = 0, i2 = 0;
  for (int mm = 0; mm < 16; ++mm) {
    int m = cg * 16 + mm;
    const float4* cp = (const float4*)(cs + m * DD);
    float a = 0.f;
#pragma unroll
    for (int q = 0; q < 32; ++q) {
      float4 cv = cp[q];
      a += rv[q].x * cv.x + rv[q].y * cv.y + rv[q].z * cv.z + rv[q].w * cv.w;
    }
    if (MODE == 1) sim[(size_t)row * KK + m] = a;
    if (a > b1) { b2 = b1; i2 = i1; b1 = a; i1 = m; }
    else if (a > b2) { b2 = a; i2 = m; }
  }
  // merge top-2 across the 4 lanes sharing this row (lanes differ in bits 0..1)
#pragma unroll
  for (int off = 1; off < 4; off <<= 1) {
    float w1 = __shfl_xor(b1, off);
    float w2 = __shfl_xor(b2, off);
    int j1 = __shfl_xor(i1, off);
    int j2 = __shfl_xor(i2, off);
    float n1, n2f; int ni1, ni2;
    if (gt_pair(b1, i1, w1, j1)) {
      n1 = b1; ni1 = i1;
      if (gt_pair(b2, i2, w1, j1)) { n2f = b2; ni2 = i2; }
      else { n2f = w1; ni2 = j1; }
    } else {
      n1 = w1; ni1 = j1;
      if (gt_pair(b1, i1, w2, j2)) { n2f = b1; ni2 = i1; }
      else { n2f = w2; ni2 = j2; }
    }
    b1 = n1; i1 = ni1; b2 = n2f; i2 = ni2;
  }
  if (cg == 0) {
    if (MODE == 0) labels[row] = i1;
    else negidx[row] = i2;
  }
}

// ---- deterministic chunked segment sum: block (m, chunk) scans CHROWS labels in fixed order
__global__ __launch_bounds__(128) void k_partial(const float* __restrict__ E,
                                                 const int* __restrict__ labels,
                                                 float* __restrict__ partial,
                                                 int* __restrict__ pcount) {
  int m = blockIdx.x, ch = blockIdx.y, t = threadIdx.x;
  __shared__ int lab[CHROWS];
  for (int q = t; q < CHROWS; q += 128) lab[q] = labels[ch * CHROWS + q];
  __syncthreads();
  float acc = 0.f;
  int cnt = 0;
  int base = ch * CHROWS;
  for (int r = 0; r < CHROWS; ++r) {
    if (lab[r] == m) {  // block-uniform branch
      acc += E[(size_t)(base + r) * DD + t];
      cnt++;
    }
  }
  partial[(size_t)(m * NCH + ch) * DD + t] = acc;
  if (t == 0) pcount[m * NCH + ch] = cnt;
}

// ---- per-centroid: reduce chunk partials, momentum update, ||c-upd||^2
__global__ __launch_bounds__(128) void k_reduce(const float* __restrict__ c,
                                                const float* __restrict__ partial,
                                                const int* __restrict__ pcount,
                                                float* __restrict__ updbuf,
                                                float* __restrict__ n2) {
  int m = blockIdx.x, t = threadIdx.x;
  float s = 0.f;
  int cnt = 0;
#pragma unroll
  for (int ch = 0; ch < NCH; ++ch) {
    s += partial[(size_t)(m * NCH + ch) * DD + t];
    cnt += pcount[m * NCH + ch];
  }
  float cv = c[m * DD + t];
  float mean = (cnt > 0) ? (s / fmaxf((float)cnt, 1.0f)) : cv;
  float u = MOM1 * cv + MOM * mean;
  updbuf[m * DD + t] = u;
  float diff = cv - u;
  float ss = diff * diff;
#pragma unroll
  for (int o = 32; o > 0; o >>= 1) ss += __shfl_down(ss, o);
  __shared__ float red[2];
  if ((t & 63) == 0) red[t >> 6] = ss;
  __syncthreads();
  if (t == 0) n2[m] = red[0] + red[1];
}

// ---- commit: all blocks compute conv identically; new_c = (done|conv) ? c : upd
__global__ __launch_bounds__(128) void k_commit(const float* __restrict__ c,
                                                const float* __restrict__ updbuf,
                                                const float* __restrict__ n2,
                                                float* __restrict__ cnext,
                                                int* __restrict__ done) {
  int m = blockIdx.x, t = threadIdx.x;
  __shared__ int ssel;
  if (t == 0) {
    bool conv = true;
    for (int j = 0; j < KK; ++j) conv = conv && (n2[j] < TOL2);
    int dn = *done;
    int sel = dn | (conv ? 1 : 0);
    ssel = sel;
    if (m == 0) *done = sel;  // idempotent w.r.t. other blocks' reads
  }
  __syncthreads();
  cnext[m * DD + t] = ssel ? c[m * DD + t] : updbuf[m * DD + t];
}

// ---- per-centroid-column top-2 rows of sim (handles diagonal exclusion downstream)
__global__ __launch_bounds__(256) void k_coltop2(const float* __restrict__ sim,
                                                 int* __restrict__ colti) {
  int m = blockIdx.x, t = threadIdx.x;
  float b1 = -3.0e38f, b2 = -3.0e38f;
  int i1 = -1, i2 = -1;
  for (int j = t; j < NN; j += 256) {
    float v = sim[(size_t)j * KK + m];
    if (v > b1) { b2 = b1; i2 = i1; b1 = v; i1 = j; }
    else if (v > b2) { b2 = v; i2 = j; }
  }
  __shared__ float s1[256], s2[256];
  __shared__ int t1[256], t2[256];
  s1[t] = b1; s2[t] = b2; t1[t] = i1; t2[t] = i2;
  __syncthreads();
  for (int o = 128; o > 0; o >>= 1) {
    if (t < o) {
      float a1 = s1[t], a2 = s2[t];
      int ai1 = t1[t], ai2 = t2[t];
      float w1 = s1[t + o], w2 = s2[t + o];
      int j1 = t1[t + o], j2 = t2[t + o];
      float n1, n2f; int ni1, ni2;
      if (gt_pair(a1, ai1, w1, j1)) {
        n1 = a1; ni1 = ai1;
        if (gt_pair(a2, ai2, w1, j1)) { n2f = a2; ni2 = ai2; }
        else { n2f = w1; ni2 = j1; }
      } else {
        n1 = w1; ni1 = j1;
        if (gt_pair(a1, ai1, w2, j2)) { n2f = a1; ni2 = ai1; }
        else { n2f = w2; ni2 = j2; }
      }
      s1[t] = n1; t1[t] = ni1; s2[t] = n2f; t2[t] = ni2;
    }
    __syncthreads();
  }
  if (t == 0) {
    colti[2 * m] = t1[0];
    colti[2 * m + 1] = t2[0];
  }
}

// ---- gather negatives: for row i with 2nd-best centroid m, pick column-top1 (or top2 if ==i)
__global__ __launch_bounds__(256) void k_gather(const float* __restrict__ E,
                                                const int* __restrict__ negidx,
                                                const int* __restrict__ colti,
                                                float* __restrict__ out) {
  int row = blockIdx.x * 2 + (threadIdx.x >> 7);
  int d = threadIdx.x & 127;
  int m = negidx[row];
  int j1 = colti[2 * m], j2 = colti[2 * m + 1];
  int j = (j1 != row) ? j1 : j2;
  out[(size_t)(KK * DD) + (size_t)row * DD + d] = E[(size_t)j * DD + d];
}

extern "C" void kernel_launch(void* const* d_in, const int* in_sizes, int n_in,
                              void* d_out, int out_size, void* d_ws, size_t ws_size,
                              hipStream_t stream) {
  const float* E = (const float*)d_in[0];
  const float* C0 = (const float*)d_in[1];
  float* out = (float*)d_out;

  // workspace carve (floats first, then ints) — total ~5.0 MB
  float* wsf = (float*)d_ws;
  float* invn   = wsf;                       // NN
  float* cbuf0  = invn + NN;                 // KK*DD
  float* cbuf1  = cbuf0 + KK * DD;           // KK*DD
  float* updbuf = cbuf1 + KK * DD;           // KK*DD
  float* n2     = updbuf + KK * DD;          // KK
  float* partial= n2 + KK;                   // KK*NCH*DD
  float* simbuf = partial + KK * NCH * DD;   // NN*KK
  int* labels = (int*)(simbuf + (size_t)NN * KK);  // NN
  int* pcount = labels + NN;                 // KK*NCH
  int* negidx = pcount + KK * NCH;           // NN
  int* colti  = negidx + NN;                 // 2*KK
  int* done   = colti + 2 * KK;              // 1

  hipMemcpyAsync(cbuf0, C0, KK * DD * sizeof(float), hipMemcpyDeviceToDevice, stream);
  k_init<<<NN / 256, 256, 0, stream>>>(E, invn, done);

  float* cc = cbuf0;
  float* cnx = cbuf1;
  for (int it = 0; it < N_ITERS; ++it) {
    k_labels<0><<<NN * 4 / 256, 256, 0, stream>>>(E, invn, cc, labels, nullptr, nullptr);
    k_partial<<<dim3(KK, NCH), 128, 0, stream>>>(E, labels, partial, pcount);
    k_reduce<<<KK, 128, 0, stream>>>(cc, partial, pcount, updbuf, n2);
    k_commit<<<KK, 128, 0, stream>>>(cc, updbuf, n2, cnx, done);
    float* tmp = cc; cc = cnx; cnx = tmp;
  }

  // final: sim + 2nd-best centroid per row, per-column top-2, gather negatives
  k_labels<1><<<NN * 4 / 256, 256, 0, stream>>>(E, invn, cc, nullptr, negidx, simbuf);
  k_coltop2<<<KK, 256, 0, stream>>>(simbuf, colti);
  hipMemcpyAsync(out, cc, KK * DD * sizeof(float), hipMemcpyDeviceToDevice, stream);
  k_gather<<<NN / 2, 256, 0, stream>>>(E, negidx, colti, out);
}

// Round 2
// 468.388 us; speedup vs baseline: 1.8671x; 1.8671x over previous
//
#include <hip/hip_runtime.h>
#include <float.h>

#define NN 16384
#define DD 128
#define KK 64
#define N_ITERS 10
#define NCHK 256          // fused blocks = row chunks
#define RPB 64            // rows per block
#define CSTR 132          // padded centroid LDS stride (floats): 132 ≡ 4 (mod 32) banks, 16B-aligned
#define EPSN 1e-12f
#define TOL2 1e-8f        // (1e-4)^2
#define MOM 0.9f
#define MOM1 0.1f

__device__ __forceinline__ bool gt_pair(float v, int i, float w, int j) {
  return (v > w) || (v == w && i < j);
}

// ---- init: inverse row norms of embeddings
__global__ __launch_bounds__(256) void k_init(const float* __restrict__ E,
                                              float* __restrict__ invn) {
  int i = blockIdx.x * 256 + threadIdx.x;
  const float4* rp = (const float4*)(E + (size_t)i * DD);
  float s = 0.f;
#pragma unroll
  for (int q = 0; q < 32; ++q) {
    float4 v = rp[q];
    s += v.x * v.x + v.y * v.y + v.z * v.z + v.w * v.w;
  }
  invn[i] = 1.0f / fmaxf(sqrtf(s), EPSN);
}

// ---- fused: commit/select centroids -> normalize -> labels -> (MODE0: per-block
//      deterministic segment partials | MODE1: transposed sim + 2nd-best centroid)
template <int MODE>
__global__ __launch_bounds__(256) void k_fused(
    const float* __restrict__ E, const float* __restrict__ invn,
    const float* __restrict__ cprev, const float* __restrict__ upd,
    const float* __restrict__ n2, int first,
    float* __restrict__ ccur,
    float* __restrict__ partial, int* __restrict__ pcount,
    int* __restrict__ negidx, float* __restrict__ simT) {
  const int t = threadIdx.x;
  const int bid = blockIdx.x;
  __shared__ float csp[KK * CSTR];   // normalized centroids, padded stride
  __shared__ float smem2[KK * DD];   // MODE0: acc[64][128]; MODE1: sim tile [64][65]
  __shared__ float cinv[KK];
  __shared__ int lab[RPB];
  __shared__ int s_sel;

  // --- convergence selection (sticky by construction: frozen c reproduces conv)
  if (t < 64) {
    bool ok = true;
    if (!first) ok = (n2[t] < TOL2);
    unsigned long long mask = __ballot(ok);
    if (t == 0) s_sel = first ? 1 : ((mask == ~0ull) ? 1 : 0);
  }

  // --- row into registers (independent of LDS phases; same math as r1)
  const int row = bid * RPB + (t >> 2);
  const int cg = t & 3;
  const float inv = invn[row];
  float4 rv[32];
  const float4* rp = (const float4*)(E + (size_t)row * DD);
#pragma unroll
  for (int q = 0; q < 32; ++q) {
    float4 v = rp[q];
    v.x *= inv; v.y *= inv; v.z *= inv; v.w *= inv;
    rv[q] = v;
  }
  __syncthreads();
  const int takeC = s_sel;

  // --- stage selected raw centroids; block 0 materializes them for k_reduce/output
  for (int e = t; e < KK * DD; e += 256) {
    float v = takeC ? cprev[e] : upd[e];
    csp[(e >> 7) * CSTR + (e & 127)] = v;
    if (bid == 0) ccur[e] = v;
  }
  __syncthreads();
  if (t < KK) {
    const float4* cm = (const float4*)(csp + t * CSTR);
    float s = 0.f;
#pragma unroll
    for (int q = 0; q < 32; ++q) {
      float4 v = cm[q];
      s += v.x * v.x + v.y * v.y + v.z * v.z + v.w * v.w;
    }
    cinv[t] = 1.0f / fmaxf(sqrtf(s), EPSN);
  }
  __syncthreads();
  for (int e = t; e < KK * DD; e += 256)
    csp[(e >> 7) * CSTR + (e & 127)] *= cinv[e >> 7];
  __syncthreads();

  // --- sim: 4 lanes/row x 16 centroids each, m interleaved (conflict-free broadcast)
  float b1 = -3.0e38f, b2 = -3.0e38f;
  int i1 = 0, i2 = 0;
  const int rloc = t >> 2;
#pragma unroll 4
  for (int mm = 0; mm < 16; ++mm) {
    const int m = mm * 4 + cg;
    const float4* cp = (const float4*)(csp + m * CSTR);
    float a = 0.f;
#pragma unroll
    for (int q = 0; q < 32; ++q) {
      float4 cv = cp[q];
      a += rv[q].x * cv.x + rv[q].y * cv.y + rv[q].z * cv.z + rv[q].w * cv.w;
    }
    if (MODE == 1) smem2[rloc * 65 + m] = a;  // sim tile (transposed write later)
    if (a > b1) { b2 = b1; i2 = i1; b1 = a; i1 = m; }
    else if (a > b2) { b2 = a; i2 = m; }
  }
  // merge top-2 across the 4 lanes of this row
#pragma unroll
  for (int off = 1; off < 4; off <<= 1) {
    float w1 = __shfl_xor(b1, off);
    float w2 = __shfl_xor(b2, off);
    int j1 = __shfl_xor(i1, off);
    int j2 = __shfl_xor(i2, off);
    float v1, v2f; int ni1, ni2;
    if (gt_pair(b1, i1, w1, j1)) {
      v1 = b1; ni1 = i1;
      if (gt_pair(b2, i2, w1, j1)) { v2f = b2; ni2 = i2; }
      else { v2f = w1; ni2 = j1; }
    } else {
      v1 = w1; ni1 = j1;
      if (gt_pair(b1, i1, w2, j2)) { v2f = b1; ni2 = i1; }
      else { v2f = w2; ni2 = j2; }
    }
    b1 = v1; i1 = ni1; b2 = v2f; i2 = ni2;
  }

  if (MODE == 0) {
    if (cg == 0) lab[rloc] = i1;
    __syncthreads();
    // zero accumulator
    for (int e = t; e < KK * DD; e += 256) smem2[e] = 0.f;
    __syncthreads();
    // deterministic segment accumulation: strictly ascending row order per slot
    if (t < 128) {
#pragma unroll 4
      for (int r = 0; r < RPB; ++r) {
        float v = E[(size_t)(bid * RPB + r) * DD + t];
        smem2[lab[r] * DD + t] += v;
      }
    } else if (t < 192) {
      const int m = t - 128;
      int c = 0;
#pragma unroll
      for (int r = 0; r < RPB; ++r) c += (lab[r] == m) ? 1 : 0;
      pcount[bid * KK + m] = c;
    }
    __syncthreads();
    for (int e = t; e < KK * DD; e += 256)
      partial[(size_t)bid * (KK * DD) + e] = smem2[e];
  } else {
    if (cg == 0) negidx[row] = i2;
    __syncthreads();
    // transposed coalesced write: simT[m][row]
    const int mT = t >> 2;
    const int rc = t & 3;
#pragma unroll
    for (int i = 0; i < 4; ++i) {
      const int r0 = rc * 16 + i * 4;
      float4 vv;
      vv.x = smem2[(r0 + 0) * 65 + mT];
      vv.y = smem2[(r0 + 1) * 65 + mT];
      vv.z = smem2[(r0 + 2) * 65 + mT];
      vv.w = smem2[(r0 + 3) * 65 + mT];
      *(float4*)&simT[(size_t)mT * NN + bid * RPB + r0] = vv;
    }
  }
}

// ---- reduce chunk partials (ascending chunk order), momentum update, ||c-upd||^2
__global__ __launch_bounds__(128) void k_reduce(const float* __restrict__ c,
                                                const float* __restrict__ partial,
                                                const int* __restrict__ pcount,
                                                float* __restrict__ upd,
                                                float* __restrict__ n2) {
  const int m = blockIdx.x, t = threadIdx.x;
  float s = 0.f;
#pragma unroll 8
  for (int ch = 0; ch < NCHK; ++ch)
    s += partial[(size_t)ch * (KK * DD) + m * DD + t];
  int cp = pcount[t * KK + m] + pcount[(t + 128) * KK + m];
#pragma unroll
  for (int off = 1; off < 64; off <<= 1) cp += __shfl_xor(cp, off);
  __shared__ int ci[2];
  __shared__ float red[2];
  if ((t & 63) == 0) ci[t >> 6] = cp;
  __syncthreads();
  const int cnt = ci[0] + ci[1];
  float cv = c[m * DD + t];
  float mean = (cnt > 0) ? (s / fmaxf((float)cnt, 1.0f)) : cv;
  float u = MOM1 * cv + MOM * mean;
  upd[m * DD + t] = u;
  float diff = cv - u;
  float ss = diff * diff;
#pragma unroll
  for (int o = 32; o > 0; o >>= 1) ss += __shfl_down(ss, o);
  if ((t & 63) == 0) red[t >> 6] = ss;
  __syncthreads();
  if (t == 0) n2[m] = red[0] + red[1];
}

// ---- per-centroid-column top-2 rows of simT (coalesced)
__global__ __launch_bounds__(256) void k_coltop2(const float* __restrict__ simT,
                                                 int* __restrict__ colti) {
  int m = blockIdx.x, t = threadIdx.x;
  float b1 = -3.0e38f, b2 = -3.0e38f;
  int i1 = -1, i2 = -1;
  for (int j = t; j < NN; j += 256) {
    float v = simT[(size_t)m * NN + j];
    if (v > b1) { b2 = b1; i2 = i1; b1 = v; i1 = j; }
    else if (v > b2) { b2 = v; i2 = j; }
  }
  __shared__ float s1[256], s2[256];
  __shared__ int t1[256], t2[256];
  s1[t] = b1; s2[t] = b2; t1[t] = i1; t2[t] = i2;
  __syncthreads();
  for (int o = 128; o > 0; o >>= 1) {
    if (t < o) {
      float a1 = s1[t], a2 = s2[t];
      int ai1 = t1[t], ai2 = t2[t];
      float w1 = s1[t + o], w2 = s2[t + o];
      int j1 = t1[t + o], j2 = t2[t + o];
      float v1, v2f; int ni1, ni2;
      if (gt_pair(a1, ai1, w1, j1)) {
        v1 = a1; ni1 = ai1;
        if (gt_pair(a2, ai2, w1, j1)) { v2f = a2; ni2 = ai2; }
        else { v2f = w1; ni2 = j1; }
      } else {
        v1 = w1; ni1 = j1;
        if (gt_pair(a1, ai1, w2, j2)) { v2f = a1; ni2 = ai1; }
        else { v2f = w2; ni2 = j2; }
      }
      s1[t] = v1; t1[t] = ni1; s2[t] = v2f; t2[t] = ni2;
    }
    __syncthreads();
  }
  if (t == 0) {
    colti[2 * m] = t1[0];
    colti[2 * m + 1] = t2[0];
  }
}

// ---- gather negatives
__global__ __launch_bounds__(256) void k_gather(const float* __restrict__ E,
                                                const int* __restrict__ negidx,
                                                const int* __restrict__ colti,
                                                float* __restrict__ out) {
  int row = blockIdx.x * 2 + (threadIdx.x >> 7);
  int d = threadIdx.x & 127;
  int m = negidx[row];
  int j1 = colti[2 * m], j2 = colti[2 * m + 1];
  int j = (j1 != row) ? j1 : j2;
  out[(size_t)(KK * DD) + (size_t)row * DD + d] = E[(size_t)j * DD + d];
}

extern "C" void kernel_launch(void* const* d_in, const int* in_sizes, int n_in,
                              void* d_out, int out_size, void* d_ws, size_t ws_size,
                              hipStream_t stream) {
  const float* E = (const float*)d_in[0];
  const float* C0 = (const float*)d_in[1];
  float* out = (float*)d_out;

  float* wsf = (float*)d_ws;
  float* invn = wsf;                            // NN
  float* cb0 = invn + NN;                       // KK*DD
  float* cb1 = cb0 + KK * DD;                   // KK*DD
  float* updb = cb1 + KK * DD;                  // KK*DD
  float* n2b = updb + KK * DD;                  // KK
  float* partial = n2b + KK;                    // NCHK*KK*DD = 8MB (aliased with simT)
  float* simT = partial;                        // KK*NN = 4MB (final pass only)
  int* pcount = (int*)(partial + (size_t)NCHK * KK * DD);  // NCHK*KK
  int* negidx = pcount + NCHK * KK;             // NN
  int* colti = negidx + NN;                     // 2*KK

  k_init<<<NN / 256, 256, 0, stream>>>(E, invn);

  float* cbs[2] = {cb0, cb1};
  for (int it = 0; it < N_ITERS; ++it) {
    const float* cprev = (it == 0) ? C0 : cbs[(it - 1) & 1];
    float* ccur = cbs[it & 1];
    k_fused<0><<<NCHK, 256, 0, stream>>>(E, invn, cprev, updb, n2b, it == 0 ? 1 : 0,
                                         ccur, partial, pcount, nullptr, nullptr);
    k_reduce<<<KK, 128, 0, stream>>>(ccur, partial, pcount, updb, n2b);
  }
  // final selection -> c_10, sim (transposed) + 2nd-best centroid per row
  k_fused<1><<<NCHK, 256, 0, stream>>>(E, invn, cbs[1], updb, n2b, 0,
                                       cbs[0], nullptr, nullptr, negidx, simT);
  k_coltop2<<<KK, 256, 0, stream>>>(simT, colti);
  hipMemcpyAsync(out, cbs[0], KK * DD * sizeof(float), hipMemcpyDeviceToDevice, stream);
  k_gather<<<NN / 2, 256, 0, stream>>>(E, negidx, colti, out);
}